// Round 8
// baseline (255.177 us; speedup 1.0000x reference)
//
#include <hip/hip_runtime.h>
#include <hip/hip_bf16.h>
#include <stdint.h>

namespace {
constexpr int kH = 64;
constexpr int kIn = 9;
constexpr int kSrcLen = 7;
constexpr int kPredLen = 10;
constexpr int kRows = 64;        // batch rows per block
constexpr int kThreads = 256;    // 4 waves
constexpr int kOutW = kPredLen * kIn;  // 90
// A layout: fragment-contiguous f16. 12 k-blocks (K=96), element (blk,row,e)
// at index (blk*64 + row)*8 + e. k 0..63 = h, 64..72 = x, 73..95 = zero.
constexpr int kABlk = 12;
constexpr int kASz = kABlk * kRows * 8;  // 6144 halves = 12288 B per buffer

typedef __attribute__((ext_vector_type(8))) _Float16 frag_a;  // 8 f16 (4 VGPRs)
typedef __attribute__((ext_vector_type(4))) float frag_cd;    // 4 fp32 acc

__device__ __forceinline__ float fast_rcp(float x) { return __builtin_amdgcn_rcpf(x); }
__device__ __forceinline__ float sigmoid_f(float x) { return fast_rcp(1.0f + __expf(-x)); }
__device__ __forceinline__ float tanh_f(float x) { return 1.0f - 2.0f * fast_rcp(__expf(2.0f * x) + 1.0f); }

__device__ __forceinline__ float ldf(const void* p, int i, int isbf) {
  if (isbf) {
    uint32_t w = ((uint32_t)((const uint16_t*)p)[i]) << 16;
    float f; __builtin_memcpy(&f, &w, 4); return f;
  }
  return ((const float*)p)[i];
}

// extended-K gate weight element B[k][n]: k<64 -> Whh, 64..72 -> Wih, else 0
__device__ __forceinline__ float gate_w(const void* Whh, const void* Wih,
                                        int n, int k, int isbf) {
  if (k < kH) return ldf(Whh, n * kH + k, isbf);
  if (k < kH + kIn) return ldf(Wih, n * kIn + (k - kH), isbf);
  return 0.0f;
}
}  // namespace

// Detect whether inputs are bf16 or fp32 by sampling src (see round-1 notes).
extern "C" __global__ void detect_dtype_kernel(const uint16_t* __restrict__ src_u16,
                                               int* __restrict__ flag) {
  const int t = threadIdx.x;
  int bad = 0;
  for (int i = t; i < 256; i += 64) {
    const uint16_t u = src_u16[i];
    const uint32_t e = (u >> 7) & 0xFF;
    const int plausible = (u == 0) || (e >= 100 && e <= 150);
    bad += !plausible;
  }
#pragma unroll
  for (int off = 32; off; off >>= 1) bad += __shfl_down(bad, off, 64);
  if (t == 0) *flag = (bad < 64) ? 1 : 0;
}

extern "C" __global__ void __launch_bounds__(kThreads)
// (2,2): exactly 2 waves/EU -> full 256-VGPR budget. waves_per_eu(3) made the
// allocator spill ALL persistent state to scratch (r7: WRITE_SIZE +84 MB).
__attribute__((amdgpu_waves_per_eu(2, 2)))
lstm_seq2seq_kernel(const void* __restrict__ src,
                    const void* __restrict__ enc_Wih,
                    const void* __restrict__ enc_Whh,
                    const void* __restrict__ enc_b,
                    const void* __restrict__ dec_Wih,
                    const void* __restrict__ dec_Whh,
                    const void* __restrict__ dec_b,
                    const void* __restrict__ fc_W,
                    const void* __restrict__ fc_b,
                    void* __restrict__ out,
                    const int* __restrict__ flag) {
  // Double-buffered A (f16, single precision pass).
  __shared__ __align__(16) _Float16 a_m[2][kASz];  // 2 x 12288 B

  const int tid = threadIdx.x;
  const int lane = tid & 63;
  const int wave = tid >> 6;
  const int quad = lane >> 4;
  const int half = lane & 15;
  const int row0 = blockIdx.x * kRows;
  const int isbf = *flag;  // grid-uniform
  const int col = wave * 16 + half;  // hidden column owned in activation phase

  // ---- zero both buffers ----
  for (int i = tid; i < kASz; i += kThreads) {
    a_m[0][i] = (_Float16)0.0f;
    a_m[1][i] = (_Float16)0.0f;
  }
  __syncthreads();

  // stage x(step 0) into buf 0: k = 64+i -> block 8+(i>>3), elem i&7
  for (int item = tid; item < kRows * kIn; item += kThreads) {
    const int r = item / kIn, i = item - r * kIn;
    const float x = ldf(src, (row0 + r) * (kSrcLen * kIn) + i, isbf);
    a_m[0][(((8 + (i >> 3)) * kRows) + r) * 8 + (i & 7)] = (_Float16)x;
  }

  // ---- persistent per-thread state ----
  float c_st[16];
#pragma unroll
  for (int i = 0; i < 16; ++i) c_st[i] = 0.0f;

  // B fragments: bm[kt][nt], nt = GATE TYPE (i,f,g,o), col = wave*16+half
  frag_a bm[3][4];
  float bias_g[4];
  frag_a fm[2];
  float fcb = 0.0f;

  auto load_gate_frags = [&](const void* Whh, const void* Wih, const void* bv) {
#pragma unroll
    for (int kt = 0; kt < 3; ++kt) {
#pragma unroll
      for (int nt = 0; nt < 4; ++nt) {
        frag_a f;
        const int n = nt * kH + col;
#pragma unroll
        for (int j = 0; j < 8; ++j) {
          const int k = kt * 32 + quad * 8 + j;
          f[j] = (_Float16)gate_w(Whh, Wih, n, k, isbf);
        }
        bm[kt][nt] = f;
      }
    }
#pragma unroll
    for (int nt = 0; nt < 4; ++nt) bias_g[nt] = ldf(bv, nt * kH + col, isbf);
  };

  // One LSTM step: read A from buf[cur], write h into buf[cur^1]. No barrier.
  auto lstm_step = [&](int cur) {
#pragma unroll 1
    for (int ch = 0; ch < 4; ++ch) {
      const int r = ch * 16 + half;
      const frag_a a0 = *(const frag_a*)&a_m[cur][((0 * 4 + quad) * kRows + r) * 8];
      const frag_a a1 = *(const frag_a*)&a_m[cur][((1 * 4 + quad) * kRows + r) * 8];
      const frag_a a2 = *(const frag_a*)&a_m[cur][((2 * 4 + quad) * kRows + r) * 8];

      frag_cd acc[4];
#pragma unroll
      for (int nt = 0; nt < 4; ++nt) {
        const float b = bias_g[nt];
        frag_cd a = {b, b, b, b};
        a = __builtin_amdgcn_mfma_f32_16x16x32_f16(a0, bm[0][nt], a, 0, 0, 0);
        a = __builtin_amdgcn_mfma_f32_16x16x32_f16(a1, bm[1][nt], a, 0, 0, 0);
        a = __builtin_amdgcn_mfma_f32_16x16x32_f16(a2, bm[2][nt], a, 0, 0, 0);
        acc[nt] = a;
      }

      // activations fully in registers: acc[0..3][j] = (gi,gf,gg,go) for
      // (row = ch*16 + quad*4 + j, col)
#pragma unroll
      for (int j = 0; j < 4; ++j) {
        const float gi = acc[0][j];
        const float gf = acc[1][j];
        const float gg = acc[2][j];
        const float go = acc[3][j];
        float c = c_st[ch * 4 + j];
        c = fmaf(sigmoid_f(gf), c, sigmoid_f(gi) * tanh_f(gg));
        c_st[ch * 4 + j] = c;
        const float h = sigmoid_f(go) * tanh_f(c);
        const int rr = ch * 16 + quad * 4 + j;
        a_m[cur ^ 1][(((col >> 3) * kRows) + rr) * 8 + (col & 7)] = (_Float16)h;
      }
    }
  };

  // ================= ENCODER =================
  load_gate_frags(enc_Whh, enc_Wih, enc_b);
  __syncthreads();  // x(0) + zero init visible

  int cur = 0;
#pragma unroll 1
  for (int s = 0; s < kSrcLen; ++s) {
    lstm_step(cur);
    // stage x for next step (or keep x(last) for decoder t=0) into buf[cur^1]
    const int ns = (s + 1 < kSrcLen) ? s + 1 : kSrcLen - 1;
    for (int item = tid; item < kRows * kIn; item += kThreads) {
      const int r = item / kIn, i = item - r * kIn;
      const float x = ldf(src, (row0 + r) * (kSrcLen * kIn) + ns * kIn + i, isbf);
      a_m[cur ^ 1][(((8 + (i >> 3)) * kRows) + r) * 8 + (i & 7)] = (_Float16)x;
    }
    __syncthreads();
    cur ^= 1;
  }

  // ================= DECODER =================
  load_gate_frags(dec_Whh, dec_Wih, dec_b);
  // fc B fragments (k-tiles 0,1 = h only; bias via acc init); B cols 0..8
#pragma unroll
  for (int kt = 0; kt < 2; ++kt) {
    frag_a f;
#pragma unroll
    for (int j = 0; j < 8; ++j) {
      const int k = kt * 32 + quad * 8 + j;
      const float v = (half < kIn) ? ldf(fc_W, half * kH + k, isbf) : 0.0f;
      f[j] = (_Float16)v;
    }
    fm[kt] = f;
  }
  fcb = (half < kIn) ? ldf(fc_b, half, isbf) : 0.0f;

#pragma unroll 1
  for (int t = 0; t < kPredLen; ++t) {
    lstm_step(cur);
    __syncthreads();
    cur ^= 1;

    // ---- fc head: wave w handles rows [w*16, w*16+16) of buf[cur] ----
    const int r = wave * 16 + half;
    const frag_a a0 = *(const frag_a*)&a_m[cur][((0 * 4 + quad) * kRows + r) * 8];
    const frag_a a1 = *(const frag_a*)&a_m[cur][((1 * 4 + quad) * kRows + r) * 8];
    frag_cd p = {fcb, fcb, fcb, fcb};
    p = __builtin_amdgcn_mfma_f32_16x16x32_f16(a0, fm[0], p, 0, 0, 0);
    p = __builtin_amdgcn_mfma_f32_16x16x32_f16(a1, fm[1], p, 0, 0, 0);

    if (half < kIn) {
#pragma unroll
      for (int j = 0; j < 4; ++j) {
        const int rr = wave * 16 + quad * 4 + j;
        const float pred = p[j];
        const int oidx = (row0 + rr) * kOutW + t * kIn + half;
        if (isbf) {
          ((__hip_bfloat16*)out)[oidx] = __float2bfloat16(pred);
        } else {
          ((float*)out)[oidx] = pred;
        }
        // feedback x into the buffer next step reads
        a_m[cur][(((8 + (half >> 3)) * kRows) + rr) * 8 + (half & 7)] = (_Float16)pred;
      }
    }
    __syncthreads();
  }
}

extern "C" void kernel_launch(void* const* d_in, const int* in_sizes, int n_in,
                              void* d_out, int out_size, void* d_ws, size_t ws_size,
                              hipStream_t stream) {
  (void)n_in; (void)ws_size; (void)out_size;
  int* flag = (int*)d_ws;

  hipLaunchKernelGGL(detect_dtype_kernel, dim3(1), dim3(64), 0, stream,
                     (const uint16_t*)d_in[0], flag);

  const int b_total = in_sizes[0] / (kSrcLen * kIn);
  const int grid = b_total / kRows;  // B=65536 -> 1024 blocks

  hipLaunchKernelGGL(lstm_seq2seq_kernel, dim3(grid), dim3(kThreads), 0, stream,
                     d_in[0], d_in[1], d_in[2], d_in[3], d_in[4], d_in[5],
                     d_in[6], d_in[7], d_in[8], d_out, flag);
}

// Round 9
// 250.158 us; speedup vs baseline: 1.0201x; 1.0201x over previous
//
#include <hip/hip_runtime.h>
#include <hip/hip_bf16.h>
#include <stdint.h>

namespace {
constexpr int kH = 64;
constexpr int kIn = 9;
constexpr int kSrcLen = 7;
constexpr int kPredLen = 10;
constexpr int kRows = 64;        // batch rows per block
constexpr int kThreads = 256;    // 4 waves
constexpr int kOutW = kPredLen * kIn;  // 90
constexpr int kBiasK = 73;       // A[.][73] = 1.0, B[73][n] = bias_n
// A layout: fragment-contiguous f16. 12 k-blocks (K=96), element (blk,row,e)
// at index (blk*64 + row)*8 + e. k 0..63 = h, 64..72 = x, 73 = 1, 74..95 = 0.
constexpr int kABlk = 12;
constexpr int kASz = kABlk * kRows * 8;  // 6144 halves = 12288 B per buffer

typedef __attribute__((ext_vector_type(8))) _Float16 frag_a;  // 8 f16 (4 VGPRs)
typedef __attribute__((ext_vector_type(4))) float frag_cd;    // 4 fp32 acc

__device__ __forceinline__ float fast_rcp(float x) { return __builtin_amdgcn_rcpf(x); }
__device__ __forceinline__ float sigmoid_f(float x) { return fast_rcp(1.0f + __expf(-x)); }
__device__ __forceinline__ float tanh_f(float x) { return 1.0f - 2.0f * fast_rcp(__expf(2.0f * x) + 1.0f); }

__device__ __forceinline__ float ldf(const void* p, int i, int isbf) {
  if (isbf) {
    uint32_t w = ((uint32_t)((const uint16_t*)p)[i]) << 16;
    float f; __builtin_memcpy(&f, &w, 4); return f;
  }
  return ((const float*)p)[i];
}

// extended-K gate weight B[k][n]: k<64 -> Whh, 64..72 -> Wih, 73 -> bias, else 0
__device__ __forceinline__ float gate_w(const void* Whh, const void* Wih,
                                        const void* bv, int n, int k, int isbf) {
  if (k < kH) return ldf(Whh, n * kH + k, isbf);
  if (k < kH + kIn) return ldf(Wih, n * kIn + (k - kH), isbf);
  if (k == kBiasK) return ldf(bv, n, isbf);
  return 0.0f;
}
}  // namespace

// Detect whether inputs are bf16 or fp32 by sampling src (see round-1 notes).
extern "C" __global__ void detect_dtype_kernel(const uint16_t* __restrict__ src_u16,
                                               int* __restrict__ flag) {
  const int t = threadIdx.x;
  int bad = 0;
  for (int i = t; i < 256; i += 64) {
    const uint16_t u = src_u16[i];
    const uint32_t e = (u >> 7) & 0xFF;
    const int plausible = (u == 0) || (e >= 100 && e <= 150);
    bad += !plausible;
  }
#pragma unroll
  for (int off = 32; off; off >>= 1) bad += __shfl_down(bad, off, 64);
  if (t == 0) *flag = (bad < 64) ? 1 : 0;
}

extern "C" __global__ void __launch_bounds__(kThreads)
// (3,3): exactly 3 waves/EU -> 170-VGPR budget (demand ~125, no spills),
// 12 waves/CU for latency hiding. (2,2) was under-occupied (r8: 207us,
// pipes <15%/SIMD); unbounded (3) spilled everything (r7: +84MB WRITE).
__attribute__((amdgpu_waves_per_eu(3, 3)))
lstm_seq2seq_kernel(const void* __restrict__ src,
                    const void* __restrict__ enc_Wih,
                    const void* __restrict__ enc_Whh,
                    const void* __restrict__ enc_b,
                    const void* __restrict__ dec_Wih,
                    const void* __restrict__ dec_Whh,
                    const void* __restrict__ dec_b,
                    const void* __restrict__ fc_W,
                    const void* __restrict__ fc_b,
                    void* __restrict__ out,
                    const int* __restrict__ flag) {
  // Double-buffered A (f16, single precision pass).
  __shared__ __align__(16) _Float16 a_m[2][kASz];  // 2 x 12288 B

  const int tid = threadIdx.x;
  const int lane = tid & 63;
  const int wave = tid >> 6;
  const int quad = lane >> 4;
  const int half = lane & 15;
  const int row0 = blockIdx.x * kRows;
  const int isbf = *flag;  // grid-uniform
  const int col = wave * 16 + half;  // hidden column owned in activation phase

  // ---- init both buffers: zeros, 1.0 in the bias column ----
  for (int i = tid; i < kASz; i += kThreads) {
    // bias column: blk 9 (k 72..79), elem 1 -> k 73
    const int e = i & 7;
    const int blk = i / (kRows * 8);
    const _Float16 v = (blk == 9 && e == 1) ? (_Float16)1.0f : (_Float16)0.0f;
    a_m[0][i] = v;
    a_m[1][i] = v;
  }
  __syncthreads();

  // per-thread encoder staging slots (fixed across steps): items tid, tid+256,
  // tid+512 of the 576-element x panel; r = item/9, i = item%9.
  const int it1_on = (tid + 256 < kRows * kIn);
  const int it2_on = (tid + 512 < kRows * kIn);
  const int r_0 = tid / kIn, i_0 = tid - r_0 * kIn;
  const int r_1 = (tid + 256) / kIn, i_1 = (tid + 256) - r_1 * kIn;
  const int r_2 = (tid + 512) / kIn, i_2 = (tid + 512) - r_2 * kIn;
  const int lds0 = (((8 + (i_0 >> 3)) * kRows) + r_0) * 8 + (i_0 & 7);
  const int lds1 = (((8 + (i_1 >> 3)) * kRows) + r_1) * 8 + (i_1 & 7);
  const int lds2 = (((8 + (i_2 >> 3)) * kRows) + r_2) * 8 + (i_2 & 7);
  const int g0 = (row0 + r_0) * (kSrcLen * kIn) + i_0;
  const int g1 = (row0 + r_1) * (kSrcLen * kIn) + i_1;
  const int g2 = (row0 + r_2) * (kSrcLen * kIn) + i_2;

  // stage x(step 0) into buf 0
  {
    a_m[0][lds0] = (_Float16)ldf(src, g0, isbf);
    if (it1_on) a_m[0][lds1] = (_Float16)ldf(src, g1, isbf);
    if (it2_on) a_m[0][lds2] = (_Float16)ldf(src, g2, isbf);
  }

  // ---- persistent per-thread state ----
  float c_st[16];
#pragma unroll
  for (int i = 0; i < 16; ++i) c_st[i] = 0.0f;

  // B fragments: bm[kt][nt], nt = GATE TYPE (i,f,g,o), col = wave*16+half
  frag_a bm[3][4];
  frag_a fm[2];
  float fcb = 0.0f;

  auto load_gate_frags = [&](const void* Whh, const void* Wih, const void* bv) {
#pragma unroll
    for (int kt = 0; kt < 3; ++kt) {
#pragma unroll
      for (int nt = 0; nt < 4; ++nt) {
        frag_a f;
        const int n = nt * kH + col;
#pragma unroll
        for (int j = 0; j < 8; ++j) {
          const int k = kt * 32 + quad * 8 + j;
          f[j] = (_Float16)gate_w(Whh, Wih, bv, n, k, isbf);
        }
        bm[kt][nt] = f;
      }
    }
  };

  // One LSTM step: read A from buf[cur], write h into buf[cur^1]. No barrier.
  auto lstm_step = [&](int cur) {
#pragma unroll 1
    for (int ch = 0; ch < 4; ++ch) {
      const int r = ch * 16 + half;
      const frag_a a0 = *(const frag_a*)&a_m[cur][((0 * 4 + quad) * kRows + r) * 8];
      const frag_a a1 = *(const frag_a*)&a_m[cur][((1 * 4 + quad) * kRows + r) * 8];
      const frag_a a2 = *(const frag_a*)&a_m[cur][((2 * 4 + quad) * kRows + r) * 8];

      frag_cd acc[4];
#pragma unroll
      for (int nt = 0; nt < 4; ++nt) {
        frag_cd a = {0.f, 0.f, 0.f, 0.f};
        a = __builtin_amdgcn_mfma_f32_16x16x32_f16(a0, bm[0][nt], a, 0, 0, 0);
        a = __builtin_amdgcn_mfma_f32_16x16x32_f16(a1, bm[1][nt], a, 0, 0, 0);
        a = __builtin_amdgcn_mfma_f32_16x16x32_f16(a2, bm[2][nt], a, 0, 0, 0);
        acc[nt] = a;
      }

      // activations fully in registers: acc[0..3][j] = (gi,gf,gg,go) for
      // (row = ch*16 + quad*4 + j, col)
#pragma unroll
      for (int j = 0; j < 4; ++j) {
        const float gi = acc[0][j];
        const float gf = acc[1][j];
        const float gg = acc[2][j];
        const float go = acc[3][j];
        float c = c_st[ch * 4 + j];
        c = fmaf(sigmoid_f(gf), c, sigmoid_f(gi) * tanh_f(gg));
        c_st[ch * 4 + j] = c;
        const float h = sigmoid_f(go) * tanh_f(c);
        const int rr = ch * 16 + quad * 4 + j;
        a_m[cur ^ 1][(((col >> 3) * kRows) + rr) * 8 + (col & 7)] = (_Float16)h;
      }
    }
  };

  // ================= ENCODER =================
  load_gate_frags(enc_Whh, enc_Wih, enc_b);
  __syncthreads();  // x(0) + init visible

  int cur = 0;
#pragma unroll 1
  for (int s = 0; s < kSrcLen; ++s) {
    // prefetch next-step x BEFORE the step so L2 latency overlaps compute
    const int ns = (s + 1 < kSrcLen) ? s + 1 : kSrcLen - 1;
    const int off = ns * kIn;
    const float x0 = ldf(src, g0 + off, isbf);
    const float x1 = it1_on ? ldf(src, g1 + off, isbf) : 0.0f;
    const float x2 = it2_on ? ldf(src, g2 + off, isbf) : 0.0f;

    lstm_step(cur);

    a_m[cur ^ 1][lds0] = (_Float16)x0;
    if (it1_on) a_m[cur ^ 1][lds1] = (_Float16)x1;
    if (it2_on) a_m[cur ^ 1][lds2] = (_Float16)x2;
    __syncthreads();
    cur ^= 1;
  }

  // ================= DECODER =================
  load_gate_frags(dec_Whh, dec_Wih, dec_b);
  // fc B fragments (k-tiles 0,1 = h only; bias via acc init); B cols 0..8
#pragma unroll
  for (int kt = 0; kt < 2; ++kt) {
    frag_a f;
#pragma unroll
    for (int j = 0; j < 8; ++j) {
      const int k = kt * 32 + quad * 8 + j;
      const float v = (half < kIn) ? ldf(fc_W, half * kH + k, isbf) : 0.0f;
      f[j] = (_Float16)v;
    }
    fm[kt] = f;
  }
  fcb = (half < kIn) ? ldf(fc_b, half, isbf) : 0.0f;

#pragma unroll 1
  for (int t = 0; t < kPredLen; ++t) {
    lstm_step(cur);
    __syncthreads();
    cur ^= 1;

    // ---- fc head: wave w handles rows [w*16, w*16+16) of buf[cur] ----
    const int r = wave * 16 + half;
    const frag_a a0 = *(const frag_a*)&a_m[cur][((0 * 4 + quad) * kRows + r) * 8];
    const frag_a a1 = *(const frag_a*)&a_m[cur][((1 * 4 + quad) * kRows + r) * 8];
    frag_cd p = {fcb, fcb, fcb, fcb};
    p = __builtin_amdgcn_mfma_f32_16x16x32_f16(a0, fm[0], p, 0, 0, 0);
    p = __builtin_amdgcn_mfma_f32_16x16x32_f16(a1, fm[1], p, 0, 0, 0);

    if (half < kIn) {
#pragma unroll
      for (int j = 0; j < 4; ++j) {
        const int rr = wave * 16 + quad * 4 + j;
        const float pred = p[j];
        const int oidx = (row0 + rr) * kOutW + t * kIn + half;
        if (isbf) {
          ((__hip_bfloat16*)out)[oidx] = __float2bfloat16(pred);
        } else {
          ((float*)out)[oidx] = pred;
        }
        // feedback x into the buffer next step reads
        a_m[cur][(((8 + (half >> 3)) * kRows) + rr) * 8 + (half & 7)] = (_Float16)pred;
      }
    }
    __syncthreads();
  }
}

extern "C" void kernel_launch(void* const* d_in, const int* in_sizes, int n_in,
                              void* d_out, int out_size, void* d_ws, size_t ws_size,
                              hipStream_t stream) {
  (void)n_in; (void)ws_size; (void)out_size;
  int* flag = (int*)d_ws;

  hipLaunchKernelGGL(detect_dtype_kernel, dim3(1), dim3(64), 0, stream,
                     (const uint16_t*)d_in[0], flag);

  const int b_total = in_sizes[0] / (kSrcLen * kIn);
  const int grid = b_total / kRows;  // B=65536 -> 1024 blocks

  hipLaunchKernelGGL(lstm_seq2seq_kernel, dim3(grid), dim3(kThreads), 0, stream,
                     d_in[0], d_in[1], d_in[2], d_in[3], d_in[4], d_in[5],
                     d_in[6], d_in[7], d_in[8], d_out, flag);
}

// Round 11
// 221.414 us; speedup vs baseline: 1.1525x; 1.1298x over previous
//
#include <hip/hip_runtime.h>
#include <hip/hip_bf16.h>
#include <stdint.h>

namespace {
constexpr int kH = 64;
constexpr int kIn = 9;
constexpr int kSrcLen = 7;
constexpr int kPredLen = 10;
constexpr int kRows = 64;        // batch rows per block
constexpr int kThreads = 256;    // 4 waves
constexpr int kOutW = kPredLen * kIn;  // 90
// A (h part): fragment-contiguous f16, 8 k-blocks (k 0..63), element
// (blk,row,e) at (blk*64+row)*8+e. x/bias live in a separate 16-wide panel
// ax[row][e]: e 0..8 = x, e 9 = 1.0 (bias), 10..15 = 0 (K-tile 2 = 16x16x16).
constexpr int kABlk = 8;
constexpr int kASz = kABlk * kRows * 8;   // 4096 halves = 8192 B per buffer
constexpr int kAxSz = kRows * 16;         // 1024 halves = 2048 B per buffer

typedef __attribute__((ext_vector_type(8))) _Float16 frag_a;   // K=32 frag (4 VGPRs)
typedef __attribute__((ext_vector_type(4))) _Float16 frag_a2;  // K=16 frag (2 VGPRs)
typedef __attribute__((ext_vector_type(4))) float frag_cd;     // 4 fp32 acc

__device__ __forceinline__ float fast_rcp(float x) { return __builtin_amdgcn_rcpf(x); }
__device__ __forceinline__ float sigmoid_f(float x) { return fast_rcp(1.0f + __expf(-x)); }
__device__ __forceinline__ float tanh_f(float x) { return 1.0f - 2.0f * fast_rcp(__expf(2.0f * x) + 1.0f); }

__device__ __forceinline__ float ldf(const void* p, int i, int isbf) {
  if (isbf) {
    uint32_t w = ((uint32_t)((const uint16_t*)p)[i]) << 16;
    float f; __builtin_memcpy(&f, &w, 4); return f;
  }
  return ((const float*)p)[i];
}
}  // namespace

// Detect whether inputs are bf16 or fp32 by sampling src (see round-1 notes).
extern "C" __global__ void detect_dtype_kernel(const uint16_t* __restrict__ src_u16,
                                               int* __restrict__ flag) {
  const int t = threadIdx.x;
  int bad = 0;
  for (int i = t; i < 256; i += 64) {
    const uint16_t u = src_u16[i];
    const uint32_t e = (u >> 7) & 0xFF;
    const int plausible = (u == 0) || (e >= 100 && e <= 150);
    bad += !plausible;
  }
#pragma unroll
  for (int off = 32; off; off >>= 1) bad += __shfl_down(bad, off, 64);
  if (t == 0) *flag = (bad < 64) ? 1 : 0;
}

extern "C" __global__ void __launch_bounds__(kThreads)
// (4,4): exactly 4 waves/EU (16 waves/CU, 4 blocks/CU — grid is 4 blocks/CU
// of work, so residency divides evenly; (3,3) left a serial 1-block tail at
// 12.5% occupancy, r9 measured 26% avg). RA budget 128 regs; demand ~110.
__attribute__((amdgpu_waves_per_eu(4, 4)))
lstm_seq2seq_kernel(const void* __restrict__ src,
                    const void* __restrict__ enc_Wih,
                    const void* __restrict__ enc_Whh,
                    const void* __restrict__ enc_b,
                    const void* __restrict__ dec_Wih,
                    const void* __restrict__ dec_Whh,
                    const void* __restrict__ dec_b,
                    const void* __restrict__ fc_W,
                    const void* __restrict__ fc_b,
                    void* __restrict__ out,
                    const int* __restrict__ flag) {
  __shared__ __align__(16) _Float16 a_m[2][kASz];   // h part, 2 x 8192 B
  __shared__ __align__(16) _Float16 ax[2][kAxSz];   // x|bias panel, 2 x 2048 B

  const int tid = threadIdx.x;
  const int lane = tid & 63;
  const int wave = tid >> 6;
  const int quad = lane >> 4;
  const int half = lane & 15;
  const int row0 = blockIdx.x * kRows;
  const int isbf = *flag;  // grid-uniform
  const int col = wave * 16 + half;  // hidden column owned in activation phase

  // ---- init: h buffers zero; ax zero except bias column e=9 = 1.0 ----
  for (int i = tid; i < kASz; i += kThreads) {
    a_m[0][i] = (_Float16)0.0f;
    a_m[1][i] = (_Float16)0.0f;
  }
  for (int i = tid; i < kAxSz; i += kThreads) {
    const _Float16 v = ((i & 15) == 9) ? (_Float16)1.0f : (_Float16)0.0f;
    ax[0][i] = v;
    ax[1][i] = v;
  }
  __syncthreads();

  // per-thread encoder staging slots (fixed across steps): items tid, tid+256,
  // tid+512 of the 576-element x panel; r = item/9, i = item%9.
  const int it1_on = (tid + 256 < kRows * kIn);
  const int it2_on = (tid + 512 < kRows * kIn);
  const int r_0 = tid / kIn, i_0 = tid - r_0 * kIn;
  const int r_1 = (tid + 256) / kIn, i_1 = (tid + 256) - r_1 * kIn;
  const int r_2 = (tid + 512) / kIn, i_2 = (tid + 512) - r_2 * kIn;
  const int lds0 = r_0 * 16 + i_0;
  const int lds1 = r_1 * 16 + i_1;
  const int lds2 = r_2 * 16 + i_2;
  const int g0 = (row0 + r_0) * (kSrcLen * kIn) + i_0;
  const int g1 = (row0 + r_1) * (kSrcLen * kIn) + i_1;
  const int g2 = (row0 + r_2) * (kSrcLen * kIn) + i_2;

  // stage x(step 0) into buf 0
  ax[0][lds0] = (_Float16)ldf(src, g0, isbf);
  if (it1_on) ax[0][lds1] = (_Float16)ldf(src, g1, isbf);
  if (it2_on) ax[0][lds2] = (_Float16)ldf(src, g2, isbf);

  // ---- persistent per-thread state ----
  float c_st[16];
#pragma unroll
  for (int i = 0; i < 16; ++i) c_st[i] = 0.0f;

  // B fragments: nt = GATE TYPE (i,f,g,o), col = wave*16+half.
  // bm0/bm1[nt] = K-tiles 0,1 (Whh, K=32 each); bm2[nt] = K-tile 2 (Wih+bias, K=16).
  frag_a bm0[4], bm1[4];
  frag_a2 bm2[4];
  frag_a fm[2];
  float fcb = 0.0f;

  auto load_gate_frags = [&](const void* Whh, const void* Wih, const void* bv) {
#pragma unroll
    for (int nt = 0; nt < 4; ++nt) {
      const int n = nt * kH + col;
      frag_a f0, f1;
#pragma unroll
      for (int j = 0; j < 8; ++j) {
        f0[j] = (_Float16)ldf(Whh, n * kH + (quad * 8 + j), isbf);
        f1[j] = (_Float16)ldf(Whh, n * kH + (32 + quad * 8 + j), isbf);
      }
      bm0[nt] = f0;
      bm1[nt] = f1;
      frag_a2 f2;
#pragma unroll
      for (int j = 0; j < 4; ++j) {
        const int k2 = quad * 4 + j;  // 0..15, global k = 64 + k2
        float v = 0.0f;
        if (k2 < kIn) v = ldf(Wih, n * kIn + k2, isbf);
        else if (k2 == kIn) v = ldf(bv, n, isbf);  // bias column (A=1)
        f2[j] = (_Float16)v;
      }
      bm2[nt] = f2;
    }
  };

  // One LSTM step: read A from buf[cur], write h into buf[cur^1]. No barrier.
  auto lstm_step = [&](int cur) {
#pragma unroll 1
    for (int ch = 0; ch < 4; ++ch) {
      const int r = ch * 16 + half;
      const frag_a a0 = *(const frag_a*)&a_m[cur][((0 * 4 + quad) * kRows + r) * 8];
      const frag_a a1 = *(const frag_a*)&a_m[cur][((1 * 4 + quad) * kRows + r) * 8];
      const frag_a2 a2 = *(const frag_a2*)&ax[cur][r * 16 + quad * 4];

      frag_cd acc[4];
#pragma unroll
      for (int nt = 0; nt < 4; ++nt) {
        frag_cd a = {0.f, 0.f, 0.f, 0.f};
        a = __builtin_amdgcn_mfma_f32_16x16x32_f16(a0, bm0[nt], a, 0, 0, 0);
        a = __builtin_amdgcn_mfma_f32_16x16x32_f16(a1, bm1[nt], a, 0, 0, 0);
        a = __builtin_amdgcn_mfma_f32_16x16x16f16(a2, bm2[nt], a, 0, 0, 0);
        acc[nt] = a;
      }

      // activations fully in registers: acc[0..3][j] = (gi,gf,gg,go) for
      // (row = ch*16 + quad*4 + j, col)
#pragma unroll
      for (int j = 0; j < 4; ++j) {
        const float gi = acc[0][j];
        const float gf = acc[1][j];
        const float gg = acc[2][j];
        const float go = acc[3][j];
        float c = c_st[ch * 4 + j];
        c = fmaf(sigmoid_f(gf), c, sigmoid_f(gi) * tanh_f(gg));
        c_st[ch * 4 + j] = c;
        const float h = sigmoid_f(go) * tanh_f(c);
        const int rr = ch * 16 + quad * 4 + j;
        a_m[cur ^ 1][(((col >> 3) * kRows) + rr) * 8 + (col & 7)] = (_Float16)h;
      }
    }
  };

  // ================= ENCODER =================
  load_gate_frags(enc_Whh, enc_Wih, enc_b);
  __syncthreads();  // x(0) + init visible

  int cur = 0;
#pragma unroll 1
  for (int s = 0; s < kSrcLen; ++s) {
    // prefetch next-step x BEFORE the step so L2 latency overlaps compute
    const int ns = (s + 1 < kSrcLen) ? s + 1 : kSrcLen - 1;
    const int off = ns * kIn;
    const float x0 = ldf(src, g0 + off, isbf);
    const float x1 = it1_on ? ldf(src, g1 + off, isbf) : 0.0f;
    const float x2 = it2_on ? ldf(src, g2 + off, isbf) : 0.0f;

    lstm_step(cur);

    ax[cur ^ 1][lds0] = (_Float16)x0;
    if (it1_on) ax[cur ^ 1][lds1] = (_Float16)x1;
    if (it2_on) ax[cur ^ 1][lds2] = (_Float16)x2;
    __syncthreads();
    cur ^= 1;
  }

  // ================= DECODER =================
  load_gate_frags(dec_Whh, dec_Wih, dec_b);
  // fc B fragments (K-tiles 0,1 = h only; bias via acc init); B cols 0..8
#pragma unroll
  for (int kt = 0; kt < 2; ++kt) {
    frag_a f;
#pragma unroll
    for (int j = 0; j < 8; ++j) {
      const int k = kt * 32 + quad * 8 + j;
      f[j] = (half < kIn) ? (_Float16)ldf(fc_W, half * kH + k, isbf) : (_Float16)0.0f;
    }
    fm[kt] = f;
  }
  fcb = (half < kIn) ? ldf(fc_b, half, isbf) : 0.0f;

#pragma unroll 1
  for (int t = 0; t < kPredLen; ++t) {
    lstm_step(cur);
    __syncthreads();
    cur ^= 1;

    // ---- fc head: wave w handles rows [w*16, w*16+16) of buf[cur] ----
    const int r = wave * 16 + half;
    const frag_a a0 = *(const frag_a*)&a_m[cur][((0 * 4 + quad) * kRows + r) * 8];
    const frag_a a1 = *(const frag_a*)&a_m[cur][((1 * 4 + quad) * kRows + r) * 8];
    frag_cd p = {fcb, fcb, fcb, fcb};
    p = __builtin_amdgcn_mfma_f32_16x16x32_f16(a0, fm[0], p, 0, 0, 0);
    p = __builtin_amdgcn_mfma_f32_16x16x32_f16(a1, fm[1], p, 0, 0, 0);

    if (half < kIn) {
#pragma unroll
      for (int j = 0; j < 4; ++j) {
        const int rr = wave * 16 + quad * 4 + j;
        const float pred = p[j];
        const int oidx = (row0 + rr) * kOutW + t * kIn + half;
        if (isbf) {
          ((__hip_bfloat16*)out)[oidx] = __float2bfloat16(pred);
        } else {
          ((float*)out)[oidx] = pred;
        }
        // feedback x into the panel the next step reads (bias col untouched)
        ax[cur][rr * 16 + half] = (_Float16)pred;
      }
    }
    __syncthreads();
  }
}

extern "C" void kernel_launch(void* const* d_in, const int* in_sizes, int n_in,
                              void* d_out, int out_size, void* d_ws, size_t ws_size,
                              hipStream_t stream) {
  (void)n_in; (void)ws_size; (void)out_size;
  int* flag = (int*)d_ws;

  hipLaunchKernelGGL(detect_dtype_kernel, dim3(1), dim3(64), 0, stream,
                     (const uint16_t*)d_in[0], flag);

  const int b_total = in_sizes[0] / (kSrcLen * kIn);
  const int grid = b_total / kRows;  // B=65536 -> 1024 blocks = 4 per CU

  hipLaunchKernelGGL(lstm_seq2seq_kernel, dim3(grid), dim3(kThreads), 0, stream,
                     d_in[0], d_in[1], d_in[2], d_in[3], d_in[4], d_in[5],
                     d_in[6], d_in[7], d_in[8], d_out, flag);
}